// Round 2
// baseline (6360.144 us; speedup 1.0000x reference)
//
#include <hip/hip_runtime.h>
#include <hip/hip_bf16.h>
#include <math.h>
#include <type_traits>

typedef __hip_bfloat16 bf16;
using short8 = __attribute__((ext_vector_type(8))) short;
using f32x4  = __attribute__((ext_vector_type(4))) float;

#define TS 2048
#define TH 16
#define TD 64
#define TE 1024
#define T3E 3072

// ---------------------------------------------------------------------------
// GEMM: C[M,N] = A[M,K] @ B[N,K]^T + bias[N], optional exact-erf GELU.
// A: fp32 or bf16 (template). B (weights), bias: fp32. C: fp32 or bf16.
// 128x128 tile, 4 waves (2x2), each wave 64x64 via 4x4 mfma_16x16x32_bf16.
// fp32 operands are converted to bf16 during LDS staging; accum is fp32.
// ---------------------------------------------------------------------------
template <typename TA, typename TC, bool GELU>
__global__ __launch_bounds__(256) void gemm_bt(
    const TA* __restrict__ A, const float* __restrict__ Bw,
    const float* __restrict__ bias, TC* __restrict__ C,
    int M, int N, int K)
{
    constexpr int LDSW = 40;
    __shared__ bf16 As[128 * LDSW];
    __shared__ bf16 Bs[128 * LDSW];

    const int t    = threadIdx.x;
    const int lane = t & 63;
    const int wave = t >> 6;
    const int wr   = wave >> 1;
    const int wc   = wave & 1;
    const int lr   = lane & 15;
    const int lq   = lane >> 4;
    const int mBase = blockIdx.y * 128;
    const int nBase = blockIdx.x * 128;

    f32x4 acc[4][4];
    for (int mi = 0; mi < 4; mi++)
        for (int ni = 0; ni < 4; ni++)
            acc[mi][ni] = (f32x4){0.f, 0.f, 0.f, 0.f};

    for (int k0 = 0; k0 < K; k0 += 32) {
        #pragma unroll
        for (int i = 0; i < 2; i++) {
            int l   = t + i * 256;
            int row = l >> 2;
            int kc  = (l & 3) * 8;
            // A-tile
            if constexpr (std::is_same_v<TA, float>) {
                const float* src = &A[(size_t)(mBase + row) * K + k0 + kc];
                float4 f0 = *(const float4*)src;
                float4 f1 = *(const float4*)(src + 4);
                bf16 tmp[8];
                tmp[0] = __float2bfloat16(f0.x); tmp[1] = __float2bfloat16(f0.y);
                tmp[2] = __float2bfloat16(f0.z); tmp[3] = __float2bfloat16(f0.w);
                tmp[4] = __float2bfloat16(f1.x); tmp[5] = __float2bfloat16(f1.y);
                tmp[6] = __float2bfloat16(f1.z); tmp[7] = __float2bfloat16(f1.w);
                *(uint4*)&As[row * LDSW + kc] = *(uint4*)tmp;
            } else {
                *(uint4*)&As[row * LDSW + kc] =
                    *(const uint4*)&A[(size_t)(mBase + row) * K + k0 + kc];
            }
            // B-tile (always fp32 weights)
            {
                const float* src = &Bw[(size_t)(nBase + row) * K + k0 + kc];
                float4 f0 = *(const float4*)src;
                float4 f1 = *(const float4*)(src + 4);
                bf16 tmp[8];
                tmp[0] = __float2bfloat16(f0.x); tmp[1] = __float2bfloat16(f0.y);
                tmp[2] = __float2bfloat16(f0.z); tmp[3] = __float2bfloat16(f0.w);
                tmp[4] = __float2bfloat16(f1.x); tmp[5] = __float2bfloat16(f1.y);
                tmp[6] = __float2bfloat16(f1.z); tmp[7] = __float2bfloat16(f1.w);
                *(uint4*)&Bs[row * LDSW + kc] = *(uint4*)tmp;
            }
        }
        __syncthreads();

        short8 af[4], bfr[4];
        #pragma unroll
        for (int mi = 0; mi < 4; mi++)
            af[mi] = *(const short8*)&As[(wr * 64 + mi * 16 + lr) * LDSW + lq * 8];
        #pragma unroll
        for (int ni = 0; ni < 4; ni++)
            bfr[ni] = *(const short8*)&Bs[(wc * 64 + ni * 16 + lr) * LDSW + lq * 8];

        #pragma unroll
        for (int mi = 0; mi < 4; mi++)
            #pragma unroll
            for (int ni = 0; ni < 4; ni++)
                acc[mi][ni] = __builtin_amdgcn_mfma_f32_16x16x32_bf16(
                    af[mi], bfr[ni], acc[mi][ni], 0, 0, 0);
        __syncthreads();
    }

    // epilogue: C/D layout col = lane&15, row = quad*4 + reg
    #pragma unroll
    for (int mi = 0; mi < 4; mi++) {
        #pragma unroll
        for (int ni = 0; ni < 4; ni++) {
            int c = nBase + wc * 64 + ni * 16 + lr;
            float bv = bias[c];
            #pragma unroll
            for (int i = 0; i < 4; i++) {
                int r = mBase + wr * 64 + mi * 16 + lq * 4 + i;
                float v = acc[mi][ni][i] + bv;
                if constexpr (GELU)
                    v = 0.5f * v * (1.0f + erff(v * 0.70710678118f));
                if constexpr (std::is_same_v<TC, bf16>)
                    C[(size_t)r * N + c] = __float2bfloat16(v);
                else
                    C[(size_t)r * N + c] = v;
            }
        }
    }
}

// ---------------------------------------------------------------------------
// Attention: one block per (b, h, q). qkv is bf16 [B*S, 3E].
// Scores row in LDS, block softmax, then P·V. attnO bf16 [B*S, E].
// ---------------------------------------------------------------------------
__global__ __launch_bounds__(256) void attn_softmax(
    const bf16* __restrict__ qkv, bf16* __restrict__ attnO)
{
    __shared__ float sc[TS];
    __shared__ float qsh[TD];
    __shared__ float red[256];

    const int t   = threadIdx.x;
    const int bid = blockIdx.x;
    const int q   = bid & (TS - 1);
    const int h   = (bid >> 11) & (TH - 1);
    const int b   = bid >> 15;

    const size_t rowQ = (size_t)(b * TS + q) * T3E + h * TD;
    if (t < TD) qsh[t] = __bfloat162float(qkv[rowQ + t]) * 0.125f;  // 1/sqrt(64)
    __syncthreads();

    float mx = -1e30f;
    for (int kk = t; kk < TS; kk += 256) {
        const uint4* kr = (const uint4*)&qkv[(size_t)(b * TS + kk) * T3E + TE + h * TD];
        float s = 0.f;
        #pragma unroll
        for (int c8 = 0; c8 < 8; c8++) {
            uint4 u = kr[c8];
            const bf16* p = (const bf16*)&u;
            #pragma unroll
            for (int j = 0; j < 8; j++)
                s += qsh[c8 * 8 + j] * __bfloat162float(p[j]);
        }
        sc[kk] = s;
        mx = fmaxf(mx, s);
    }
    red[t] = mx;
    __syncthreads();
    for (int off = 128; off > 0; off >>= 1) {
        if (t < off) red[t] = fmaxf(red[t], red[t + off]);
        __syncthreads();
    }
    mx = red[0];
    __syncthreads();

    float sum = 0.f;
    for (int kk = t; kk < TS; kk += 256) {
        float p = __expf(sc[kk] - mx);
        sc[kk] = p;
        sum += p;
    }
    red[t] = sum;
    __syncthreads();
    for (int off = 128; off > 0; off >>= 1) {
        if (t < off) red[t] += red[t + off];
        __syncthreads();
    }
    const float rdenom = 1.0f / red[0];
    __syncthreads();

    const int d  = t & 63;
    const int ch = t >> 6;
    const size_t vbase = (size_t)(b * TS) * T3E + 2 * TE + h * TD + d;
    float acc = 0.f;
    const int kk0 = ch * 512;
    for (int kk = kk0; kk < kk0 + 512; kk++)
        acc += sc[kk] * __bfloat162float(qkv[vbase + (size_t)kk * T3E]);
    red[t] = acc;
    __syncthreads();
    if (t < 64) {
        float o = (red[t] + red[t + 64] + red[t + 128] + red[t + 192]) * rdenom;
        attnO[(size_t)(b * TS + q) * TE + h * TD + t] = __float2bfloat16(o);
    }
}

// ---------------------------------------------------------------------------
// out = LayerNorm(a + b) * g + beta  (all fp32), one block per row of 1024
// ---------------------------------------------------------------------------
__global__ __launch_bounds__(256) void add_ln(
    const float* __restrict__ a, const float* __restrict__ bsrc,
    const float* __restrict__ g, const float* __restrict__ beta,
    float* __restrict__ out)
{
    __shared__ float r1[256], r2[256];
    const int t = threadIdx.x;
    const size_t row = (size_t)blockIdx.x * TE;

    float4 va = *(const float4*)&a[row + t * 4];
    float4 vb = *(const float4*)&bsrc[row + t * 4];
    float v[4] = {va.x + vb.x, va.y + vb.y, va.z + vb.z, va.w + vb.w};
    float s = 0.f, s2 = 0.f;
    #pragma unroll
    for (int i = 0; i < 4; i++) { s += v[i]; s2 += v[i] * v[i]; }
    r1[t] = s; r2[t] = s2;
    __syncthreads();
    for (int off = 128; off > 0; off >>= 1) {
        if (t < off) { r1[t] += r1[t + off]; r2[t] += r2[t + off]; }
        __syncthreads();
    }
    const float mu  = r1[0] * (1.f / 1024.f);
    const float var = r2[0] * (1.f / 1024.f) - mu * mu;
    const float rs  = rsqrtf(var + 1e-5f);
    float4 vg = *(const float4*)&g[t * 4];
    float4 vbt = *(const float4*)&beta[t * 4];
    float4 o;
    o.x = (v[0] - mu) * rs * vg.x + vbt.x;
    o.y = (v[1] - mu) * rs * vg.y + vbt.y;
    o.z = (v[2] - mu) * rs * vg.z + vbt.z;
    o.w = (v[3] - mu) * rs * vg.w + vbt.w;
    *(float4*)&out[row + t * 4] = o;
}

// ---------------------------------------------------------------------------
extern "C" void kernel_launch(void* const* d_in, const int* in_sizes, int n_in,
                              void* d_out, int out_size, void* d_ws, size_t ws_size,
                              hipStream_t stream)
{
    const float* x     = (const float*)d_in[0];
    const float* w_qkv = (const float*)d_in[1];
    const float* b_qkv = (const float*)d_in[2];
    const float* w_out = (const float*)d_in[3];
    const float* b_out = (const float*)d_in[4];
    const float* g1    = (const float*)d_in[5];
    const float* beta1 = (const float*)d_in[6];
    const float* w_fc1 = (const float*)d_in[7];
    const float* b_fc1 = (const float*)d_in[8];
    const float* w_fc2 = (const float*)d_in[9];
    const float* b_fc2 = (const float*)d_in[10];
    const float* g2    = (const float*)d_in[11];
    const float* beta2 = (const float*)d_in[12];
    float* out = (float*)d_out;

    // workspace (byte offsets), aliased to keep peak ~75.5 MB:
    //  [0, 33.5MB)    : qkv bf16 (k1-k2)  then hbuf bf16 (k5-k6)
    //  [33.5, 42MB)   : attnO bf16 (k2-k3)
    //  [42, 58.7MB)   : y fp32 (k3-k4)    then ff fp32 (k6-k7)
    //  [58.7, 75.5MB) : x1 fp32 (k4-k7)
    char* wsb  = (char*)d_ws;
    bf16*  qkv   = (bf16*)wsb;
    bf16*  hbuf  = (bf16*)wsb;
    bf16*  attnO = (bf16*)(wsb + 33554432);
    float* y     = (float*)(wsb + 41943040);
    float* ff    = y;
    float* x1    = (float*)(wsb + 58720256);

    const int M = 2 * TS;  // 4096 tokens
    dim3 blk(256);

    // 1) qkv = x @ w_qkv^T + b_qkv            (fp32 in, bf16 out)
    gemm_bt<float, bf16, false><<<dim3(T3E / 128, M / 128), blk, 0, stream>>>(
        x, w_qkv, b_qkv, qkv, M, T3E, TE);
    // 2) attention (bf16 qkv -> bf16 attnO)
    attn_softmax<<<dim3(2 * TH * TS), blk, 0, stream>>>(qkv, attnO);
    // 3) y = attnO @ w_out^T + b_out          (bf16 in, fp32 out)
    gemm_bt<bf16, float, false><<<dim3(TE / 128, M / 128), blk, 0, stream>>>(
        attnO, w_out, b_out, y, M, TE, TE);
    // 4) x1 = LN(x + y) * g1 + beta1
    add_ln<<<dim3(M), blk, 0, stream>>>(x, y, g1, beta1, x1);
    // 5) h = gelu(x1 @ w_fc1^T + b_fc1)       (fp32 in, bf16 out, GELU)
    gemm_bt<float, bf16, true><<<dim3(4096 / 128, M / 128), blk, 0, stream>>>(
        x1, w_fc1, b_fc1, hbuf, M, 4096, TE);
    // 6) ff = hbuf @ w_fc2^T + b_fc2          (bf16 in, fp32 out)
    gemm_bt<bf16, float, false><<<dim3(TE / 128, M / 128), blk, 0, stream>>>(
        hbuf, w_fc2, b_fc2, ff, M, TE, 4096);
    // 7) out = LN(x1 + ff) * g2 + beta2
    add_ln<<<dim3(M), blk, 0, stream>>>(x1, ff, g2, beta2, out);
}

// Round 3
// 551.166 us; speedup vs baseline: 11.5394x; 11.5394x over previous
//
#include <hip/hip_runtime.h>
#include <hip/hip_bf16.h>
#include <math.h>
#include <type_traits>

typedef __hip_bfloat16 bf16;
using short8 = __attribute__((ext_vector_type(8))) short;
using f32x4  = __attribute__((ext_vector_type(4))) float;

#define TS 2048
#define TH 16
#define TD 64
#define TE 1024
#define T3E 3072

// ---------------------------------------------------------------------------
// GEMM: C[M,N] = A[M,K] @ B[N,K]^T + bias[N], optional exact-erf GELU.
// (unchanged from round 1 — passed)
// ---------------------------------------------------------------------------
template <typename TA, typename TC, bool GELU>
__global__ __launch_bounds__(256) void gemm_bt(
    const TA* __restrict__ A, const float* __restrict__ Bw,
    const float* __restrict__ bias, TC* __restrict__ C,
    int M, int N, int K)
{
    constexpr int LDSW = 40;
    __shared__ bf16 As[128 * LDSW];
    __shared__ bf16 Bs[128 * LDSW];

    const int t    = threadIdx.x;
    const int lane = t & 63;
    const int wave = t >> 6;
    const int wr   = wave >> 1;
    const int wc   = wave & 1;
    const int lr   = lane & 15;
    const int lq   = lane >> 4;
    const int mBase = blockIdx.y * 128;
    const int nBase = blockIdx.x * 128;

    f32x4 acc[4][4];
    for (int mi = 0; mi < 4; mi++)
        for (int ni = 0; ni < 4; ni++)
            acc[mi][ni] = (f32x4){0.f, 0.f, 0.f, 0.f};

    for (int k0 = 0; k0 < K; k0 += 32) {
        #pragma unroll
        for (int i = 0; i < 2; i++) {
            int l   = t + i * 256;
            int row = l >> 2;
            int kc  = (l & 3) * 8;
            if constexpr (std::is_same_v<TA, float>) {
                const float* src = &A[(size_t)(mBase + row) * K + k0 + kc];
                float4 f0 = *(const float4*)src;
                float4 f1 = *(const float4*)(src + 4);
                bf16 tmp[8];
                tmp[0] = __float2bfloat16(f0.x); tmp[1] = __float2bfloat16(f0.y);
                tmp[2] = __float2bfloat16(f0.z); tmp[3] = __float2bfloat16(f0.w);
                tmp[4] = __float2bfloat16(f1.x); tmp[5] = __float2bfloat16(f1.y);
                tmp[6] = __float2bfloat16(f1.z); tmp[7] = __float2bfloat16(f1.w);
                *(uint4*)&As[row * LDSW + kc] = *(uint4*)tmp;
            } else {
                *(uint4*)&As[row * LDSW + kc] =
                    *(const uint4*)&A[(size_t)(mBase + row) * K + k0 + kc];
            }
            {
                const float* src = &Bw[(size_t)(nBase + row) * K + k0 + kc];
                float4 f0 = *(const float4*)src;
                float4 f1 = *(const float4*)(src + 4);
                bf16 tmp[8];
                tmp[0] = __float2bfloat16(f0.x); tmp[1] = __float2bfloat16(f0.y);
                tmp[2] = __float2bfloat16(f0.z); tmp[3] = __float2bfloat16(f0.w);
                tmp[4] = __float2bfloat16(f1.x); tmp[5] = __float2bfloat16(f1.y);
                tmp[6] = __float2bfloat16(f1.z); tmp[7] = __float2bfloat16(f1.w);
                *(uint4*)&Bs[row * LDSW + kc] = *(uint4*)tmp;
            }
        }
        __syncthreads();

        short8 af[4], bfr[4];
        #pragma unroll
        for (int mi = 0; mi < 4; mi++)
            af[mi] = *(const short8*)&As[(wr * 64 + mi * 16 + lr) * LDSW + lq * 8];
        #pragma unroll
        for (int ni = 0; ni < 4; ni++)
            bfr[ni] = *(const short8*)&Bs[(wc * 64 + ni * 16 + lr) * LDSW + lq * 8];

        #pragma unroll
        for (int mi = 0; mi < 4; mi++)
            #pragma unroll
            for (int ni = 0; ni < 4; ni++)
                acc[mi][ni] = __builtin_amdgcn_mfma_f32_16x16x32_bf16(
                    af[mi], bfr[ni], acc[mi][ni], 0, 0, 0);
        __syncthreads();
    }

    #pragma unroll
    for (int mi = 0; mi < 4; mi++) {
        #pragma unroll
        for (int ni = 0; ni < 4; ni++) {
            int c = nBase + wc * 64 + ni * 16 + lr;
            float bv = bias[c];
            #pragma unroll
            for (int i = 0; i < 4; i++) {
                int r = mBase + wr * 64 + mi * 16 + lq * 4 + i;
                float v = acc[mi][ni][i] + bv;
                if constexpr (GELU)
                    v = 0.5f * v * (1.0f + erff(v * 0.70710678118f));
                if constexpr (std::is_same_v<TC, bf16>)
                    C[(size_t)r * N + c] = __float2bfloat16(v);
                else
                    C[(size_t)r * N + c] = v;
            }
        }
    }
}

// ---------------------------------------------------------------------------
// Flash attention (MFMA). Grid (16 q-tiles, B*H=32), 256 threads (4 waves).
// Each wave: 32 q-rows x all 128 keys of the key-block. Online softmax is
// wave-internal (in-reg over 8 n-frags + shfl_xor within 16-lane group).
// LDS: K-block [128][72] unioned with Vt [64][136] (stage V after S-compute,
// 2 extra barriers, keeps total at 53 KB). P converts C-layout -> A-layout
// via per-wave LDS round trip [32][136].
// ---------------------------------------------------------------------------
#define FA_SK 72
#define FA_SV 136
#define FA_SP 136

__global__ __launch_bounds__(256, 2) void attn_flash(
    const bf16* __restrict__ qkv, bf16* __restrict__ attnO)
{
    __shared__ bf16 KV[128 * FA_SK];            // 18432 B (Vt: 64*136*2=17408 fits)
    __shared__ bf16 Ps[4 * 32 * FA_SP];         // 34816 B

    bf16* Ks = KV;
    bf16* Vt = KV;

    const int t    = threadIdx.x;
    const int lane = t & 63;
    const int wv   = t >> 6;        // 0..3: q-subtile
    const int lr   = lane & 15;
    const int lq   = lane >> 4;     // quad
    const int qt   = blockIdx.x;    // 0..15
    const int h    = blockIdx.y & 15;
    const int b    = blockIdx.y >> 4;

    const size_t tokBase = (size_t)b * TS;

    // Q fragments (A-layout): rows qt*128 + wv*32 + mi*16 + lr, k = kc*32+lq*8+j
    short8 qf[2][2];
    #pragma unroll
    for (int mi = 0; mi < 2; mi++)
        #pragma unroll
        for (int kc = 0; kc < 2; kc++)
            qf[mi][kc] = *(const short8*)&qkv[
                (tokBase + qt * 128 + wv * 32 + mi * 16 + lr) * T3E
                + h * TD + kc * 32 + lq * 8];

    f32x4 oacc[2][4];
    #pragma unroll
    for (int mi = 0; mi < 2; mi++)
        #pragma unroll
        for (int ni = 0; ni < 4; ni++)
            oacc[mi][ni] = (f32x4){0.f, 0.f, 0.f, 0.f};
    float mrow[2][4], lrow[2][4];
    #pragma unroll
    for (int mi = 0; mi < 2; mi++)
        #pragma unroll
        for (int r = 0; r < 4; r++) { mrow[mi][r] = -1e30f; lrow[mi][r] = 0.f; }

    for (int it = 0; it < 16; it++) {
        const int kb0 = it * 128;
        __syncthreads();   // protect KV union from previous iteration's PV reads

        // stage K-block [128 keys][64 d], coalesced
        #pragma unroll
        for (int i = 0; i < 4; i++) {
            int l  = t + i * 256;
            int r  = l >> 3;
            int ch = (l & 7) * 8;
            *(uint4*)&Ks[r * FA_SK + ch] =
                *(const uint4*)&qkv[(tokBase + kb0 + r) * T3E + TE + h * TD + ch];
        }
        __syncthreads();

        // S = Q K^T  (per wave: [32 q][128 k])
        f32x4 sacc[2][8];
        #pragma unroll
        for (int mi = 0; mi < 2; mi++)
            #pragma unroll
            for (int ni = 0; ni < 8; ni++)
                sacc[mi][ni] = (f32x4){0.f, 0.f, 0.f, 0.f};
        #pragma unroll
        for (int kc = 0; kc < 2; kc++) {
            short8 kf[8];
            #pragma unroll
            for (int ni = 0; ni < 8; ni++)
                kf[ni] = *(const short8*)&Ks[(ni * 16 + lr) * FA_SK + kc * 32 + lq * 8];
            #pragma unroll
            for (int mi = 0; mi < 2; mi++)
                #pragma unroll
                for (int ni = 0; ni < 8; ni++)
                    sacc[mi][ni] = __builtin_amdgcn_mfma_f32_16x16x32_bf16(
                        qf[mi][kc], kf[ni], sacc[mi][ni], 0, 0, 0);
        }

        // V global loads (independent of LDS) — issue before the barrier
        uint4 vreg[4];
        const int vr  = t >> 1;
        const int vdc = (t & 1) * 32;
        #pragma unroll
        for (int i = 0; i < 4; i++)
            vreg[i] = *(const uint4*)&qkv[
                (tokBase + kb0 + vr) * T3E + 2 * TE + h * TD + vdc + i * 8];

        __syncthreads();   // all waves done reading Ks; KV region now free for Vt

        // write V transposed: Vt[d][key]
        {
            const bf16* vv = (const bf16*)vreg;
            #pragma unroll
            for (int j = 0; j < 32; j++)
                Vt[(vdc + j) * FA_SV + vr] = vv[j];
        }

        // online softmax (wave-internal). S C-layout: q=mi*16+lq*4+reg, k=ni*16+lr
        #pragma unroll
        for (int mi = 0; mi < 2; mi++) {
            #pragma unroll
            for (int rg = 0; rg < 4; rg++) {
                float rmax = -1e30f;
                #pragma unroll
                for (int ni = 0; ni < 8; ni++)
                    rmax = fmaxf(rmax, sacc[mi][ni][rg]);
                rmax *= 0.125f;   // scale = 1/sqrt(64), >0 so commutes with max
                #pragma unroll
                for (int m = 1; m <= 8; m <<= 1)
                    rmax = fmaxf(rmax, __shfl_xor(rmax, m, 64));
                float mnew  = fmaxf(mrow[mi][rg], rmax);
                float alpha = __expf(mrow[mi][rg] - mnew);
                mrow[mi][rg] = mnew;
                float rsum = 0.f;
                #pragma unroll
                for (int ni = 0; ni < 8; ni++) {
                    float p = __expf(sacc[mi][ni][rg] * 0.125f - mnew);
                    sacc[mi][ni][rg] = p;
                    rsum += p;
                }
                #pragma unroll
                for (int m = 1; m <= 8; m <<= 1)
                    rsum += __shfl_xor(rsum, m, 64);
                lrow[mi][rg] = lrow[mi][rg] * alpha + rsum;
                #pragma unroll
                for (int ni = 0; ni < 4; ni++)
                    oacc[mi][ni][rg] *= alpha;
            }
        }

        // write P to per-wave LDS region ([32 q][128 k], bf16)
        #pragma unroll
        for (int mi = 0; mi < 2; mi++)
            #pragma unroll
            for (int ni = 0; ni < 8; ni++)
                #pragma unroll
                for (int rg = 0; rg < 4; rg++)
                    Ps[(wv * 32 + mi * 16 + lq * 4 + rg) * FA_SP + ni * 16 + lr] =
                        __float2bfloat16(sacc[mi][ni][rg]);

        __syncthreads();   // Vt fully staged (Ps is same-wave, covered too)

        // O += P V  (per wave: [32 q][64 d])
        #pragma unroll
        for (int kc = 0; kc < 4; kc++) {
            short8 pa[2], vb[4];
            #pragma unroll
            for (int mi = 0; mi < 2; mi++)
                pa[mi] = *(const short8*)&Ps[(wv * 32 + mi * 16 + lr) * FA_SP + kc * 32 + lq * 8];
            #pragma unroll
            for (int ni = 0; ni < 4; ni++)
                vb[ni] = *(const short8*)&Vt[(ni * 16 + lr) * FA_SV + kc * 32 + lq * 8];
            #pragma unroll
            for (int mi = 0; mi < 2; mi++)
                #pragma unroll
                for (int ni = 0; ni < 4; ni++)
                    oacc[mi][ni] = __builtin_amdgcn_mfma_f32_16x16x32_bf16(
                        pa[mi], vb[ni], oacc[mi][ni], 0, 0, 0);
        }
    }

    // epilogue: O /= l, write attnO [token][E]
    #pragma unroll
    for (int mi = 0; mi < 2; mi++) {
        #pragma unroll
        for (int ni = 0; ni < 4; ni++) {
            #pragma unroll
            for (int rg = 0; rg < 4; rg++) {
                float o = oacc[mi][ni][rg] / lrow[mi][rg];
                attnO[(tokBase + qt * 128 + wv * 32 + mi * 16 + lq * 4 + rg) * TE
                      + h * TD + ni * 16 + lr] = __float2bfloat16(o);
            }
        }
    }
}

// ---------------------------------------------------------------------------
// out = LayerNorm(a + b) * g + beta  (all fp32), one block per row of 1024
// ---------------------------------------------------------------------------
__global__ __launch_bounds__(256) void add_ln(
    const float* __restrict__ a, const float* __restrict__ bsrc,
    const float* __restrict__ g, const float* __restrict__ beta,
    float* __restrict__ out)
{
    __shared__ float r1[256], r2[256];
    const int t = threadIdx.x;
    const size_t row = (size_t)blockIdx.x * TE;

    float4 va = *(const float4*)&a[row + t * 4];
    float4 vb = *(const float4*)&bsrc[row + t * 4];
    float v[4] = {va.x + vb.x, va.y + vb.y, va.z + vb.z, va.w + vb.w};
    float s = 0.f, s2 = 0.f;
    #pragma unroll
    for (int i = 0; i < 4; i++) { s += v[i]; s2 += v[i] * v[i]; }
    r1[t] = s; r2[t] = s2;
    __syncthreads();
    for (int off = 128; off > 0; off >>= 1) {
        if (t < off) { r1[t] += r1[t + off]; r2[t] += r2[t + off]; }
        __syncthreads();
    }
    const float mu  = r1[0] * (1.f / 1024.f);
    const float var = r2[0] * (1.f / 1024.f) - mu * mu;
    const float rs  = rsqrtf(var + 1e-5f);
    float4 vg = *(const float4*)&g[t * 4];
    float4 vbt = *(const float4*)&beta[t * 4];
    float4 o;
    o.x = (v[0] - mu) * rs * vg.x + vbt.x;
    o.y = (v[1] - mu) * rs * vg.y + vbt.y;
    o.z = (v[2] - mu) * rs * vg.z + vbt.z;
    o.w = (v[3] - mu) * rs * vg.w + vbt.w;
    *(float4*)&out[row + t * 4] = o;
}

// ---------------------------------------------------------------------------
extern "C" void kernel_launch(void* const* d_in, const int* in_sizes, int n_in,
                              void* d_out, int out_size, void* d_ws, size_t ws_size,
                              hipStream_t stream)
{
    const float* x     = (const float*)d_in[0];
    const float* w_qkv = (const float*)d_in[1];
    const float* b_qkv = (const float*)d_in[2];
    const float* w_out = (const float*)d_in[3];
    const float* b_out = (const float*)d_in[4];
    const float* g1    = (const float*)d_in[5];
    const float* beta1 = (const float*)d_in[6];
    const float* w_fc1 = (const float*)d_in[7];
    const float* b_fc1 = (const float*)d_in[8];
    const float* w_fc2 = (const float*)d_in[9];
    const float* b_fc2 = (const float*)d_in[10];
    const float* g2    = (const float*)d_in[11];
    const float* beta2 = (const float*)d_in[12];
    float* out = (float*)d_out;

    // workspace (byte offsets), peak ~75.5 MB:
    //  [0, 33.5MB)    : qkv bf16 (k1-k2)  then hbuf bf16 (k5-k6)
    //  [33.5, 42MB)   : attnO bf16 (k2-k3)
    //  [42, 58.7MB)   : y fp32 (k3-k4)    then ff fp32 (k6-k7)
    //  [58.7, 75.5MB) : x1 fp32 (k4-k7)
    char* wsb  = (char*)d_ws;
    bf16*  qkv   = (bf16*)wsb;
    bf16*  hbuf  = (bf16*)wsb;
    bf16*  attnO = (bf16*)(wsb + 33554432);
    float* y     = (float*)(wsb + 41943040);
    float* ff    = y;
    float* x1    = (float*)(wsb + 58720256);

    const int M = 2 * TS;  // 4096 tokens
    dim3 blk(256);

    // 1) qkv = x @ w_qkv^T + b_qkv            (fp32 in, bf16 out)
    gemm_bt<float, bf16, false><<<dim3(T3E / 128, M / 128), blk, 0, stream>>>(
        x, w_qkv, b_qkv, qkv, M, T3E, TE);
    // 2) flash attention (bf16 qkv -> bf16 attnO)
    attn_flash<<<dim3(TS / 128, 2 * TH), blk, 0, stream>>>(qkv, attnO);
    // 3) y = attnO @ w_out^T + b_out          (bf16 in, fp32 out)
    gemm_bt<bf16, float, false><<<dim3(TE / 128, M / 128), blk, 0, stream>>>(
        attnO, w_out, b_out, y, M, TE, TE);
    // 4) x1 = LN(x + y) * g1 + beta1
    add_ln<<<dim3(M), blk, 0, stream>>>(x, y, g1, beta1, x1);
    // 5) h = gelu(x1 @ w_fc1^T + b_fc1)       (fp32 in, bf16 out, GELU)
    gemm_bt<float, bf16, true><<<dim3(4096 / 128, M / 128), blk, 0, stream>>>(
        x1, w_fc1, b_fc1, hbuf, M, 4096, TE);
    // 6) ff = hbuf @ w_fc2^T + b_fc2          (bf16 in, fp32 out)
    gemm_bt<bf16, float, false><<<dim3(TE / 128, M / 128), blk, 0, stream>>>(
        hbuf, w_fc2, b_fc2, ff, M, TE, 4096);
    // 7) out = LN(x1 + ff) * g2 + beta2
    add_ln<<<dim3(M), blk, 0, stream>>>(x1, ff, g2, beta2, out);
}

// Round 4
// 436.847 us; speedup vs baseline: 14.5592x; 1.2617x over previous
//
#include <hip/hip_runtime.h>
#include <hip/hip_bf16.h>
#include <math.h>
#include <type_traits>

typedef __hip_bfloat16 bf16;
using short8 = __attribute__((ext_vector_type(8))) short;
using f32x4  = __attribute__((ext_vector_type(4))) float;

#define TS 2048
#define TH 16
#define TD 64
#define TE 1024
#define T3E 3072

// async global->LDS, 16B per lane; lds base must be wave-uniform,
// HW scatters lane i to ldsbase + i*16.
__device__ __forceinline__ void gload16(void* lds, const void* g) {
    __builtin_amdgcn_global_load_lds(
        (__attribute__((address_space(1))) void*)g,
        (__attribute__((address_space(3))) void*)lds, 16, 0, 0);
}

// ---------------------------------------------------------------------------
// fp32 -> bf16 bulk convert, 8 elems/thread (n must be multiple of 2048)
// ---------------------------------------------------------------------------
__global__ __launch_bounds__(256) void f2b(
    const float* __restrict__ s, bf16* __restrict__ d)
{
    size_t i = ((size_t)blockIdx.x * 256 + threadIdx.x) * 8;
    float4 a = *(const float4*)&s[i];
    float4 b = *(const float4*)&s[i + 4];
    bf16 t[8];
    t[0] = __float2bfloat16(a.x); t[1] = __float2bfloat16(a.y);
    t[2] = __float2bfloat16(a.z); t[3] = __float2bfloat16(a.w);
    t[4] = __float2bfloat16(b.x); t[5] = __float2bfloat16(b.y);
    t[6] = __float2bfloat16(b.z); t[7] = __float2bfloat16(b.w);
    *(uint4*)&d[i] = *(uint4*)t;
}

// ---------------------------------------------------------------------------
// GEMM (m97 structure): C[M,N] = A[M,K] @ B[N,K]^T (+bias, +GELU opt).
// A, B bf16; C fp32 or bf16. 128x128 tile, 4 waves 2x2, 4x4 frags,
// mfma_16x16x32_bf16. Staging via global_load_lds width=16 into contiguous
// As/Bs[128][32]. Split-K via gridDim.z: block z handles K range
// [z*kLen, (z+1)*kLen), writes to C + z*M*N; bias only on z==0.
// ---------------------------------------------------------------------------
template <typename TC, bool GELU>
__global__ __launch_bounds__(256) void gemm_bt(
    const bf16* __restrict__ A, const bf16* __restrict__ Bw,
    const float* __restrict__ bias, TC* __restrict__ C,
    int M, int N, int K, int kLen)
{
    __shared__ bf16 As[128 * 32];
    __shared__ bf16 Bs[128 * 32];

    const int t    = threadIdx.x;
    const int lane = t & 63;
    const int wave = t >> 6;
    const int wr   = wave >> 1;
    const int wc   = wave & 1;
    const int lr   = lane & 15;
    const int lq   = lane >> 4;
    const int mBase = blockIdx.y * 128;
    const int nBase = blockIdx.x * 128;
    const int kOff  = blockIdx.z * kLen;

    const int srow = lane >> 2;        // staging: row within 16-row chunk
    const int skc  = (lane & 3) * 8;   // staging: k-offset (8 bf16 = 16B)

    f32x4 acc[4][4];
    #pragma unroll
    for (int mi = 0; mi < 4; mi++)
        #pragma unroll
        for (int ni = 0; ni < 4; ni++)
            acc[mi][ni] = (f32x4){0.f, 0.f, 0.f, 0.f};

    for (int k0 = kOff; k0 < kOff + kLen; k0 += 32) {
        // each wave stages 2x16 rows of A and of B (1024B per call)
        #pragma unroll
        for (int c = 0; c < 2; c++) {
            int r0 = wave * 32 + c * 16;
            gload16(&As[r0 * 32],
                    &A[(size_t)(mBase + r0 + srow) * K + k0 + skc]);
            gload16(&Bs[r0 * 32],
                    &Bw[(size_t)(nBase + r0 + srow) * K + k0 + skc]);
        }
        __syncthreads();   // compiler drains vmcnt before barrier

        short8 af[4], bfr[4];
        #pragma unroll
        for (int mi = 0; mi < 4; mi++)
            af[mi] = *(const short8*)&As[(wr * 64 + mi * 16 + lr) * 32 + lq * 8];
        #pragma unroll
        for (int ni = 0; ni < 4; ni++)
            bfr[ni] = *(const short8*)&Bs[(wc * 64 + ni * 16 + lr) * 32 + lq * 8];

        #pragma unroll
        for (int mi = 0; mi < 4; mi++)
            #pragma unroll
            for (int ni = 0; ni < 4; ni++)
                acc[mi][ni] = __builtin_amdgcn_mfma_f32_16x16x32_bf16(
                    af[mi], bfr[ni], acc[mi][ni], 0, 0, 0);
        __syncthreads();
    }

    const size_t cOff = (size_t)blockIdx.z * M * N;
    #pragma unroll
    for (int mi = 0; mi < 4; mi++) {
        #pragma unroll
        for (int ni = 0; ni < 4; ni++) {
            int c = nBase + wc * 64 + ni * 16 + lr;
            float bv = (blockIdx.z == 0) ? bias[c] : 0.f;
            #pragma unroll
            for (int i = 0; i < 4; i++) {
                int r = mBase + wr * 64 + mi * 16 + lq * 4 + i;
                float v = acc[mi][ni][i] + bv;
                if constexpr (GELU)
                    v = 0.5f * v * (1.0f + erff(v * 0.70710678118f));
                if constexpr (std::is_same_v<TC, bf16>)
                    C[cOff + (size_t)r * N + c] = __float2bfloat16(v);
                else
                    C[cOff + (size_t)r * N + c] = v;
            }
        }
    }
}

// ---------------------------------------------------------------------------
// Flash attention (unchanged from round 3 — verified)
// ---------------------------------------------------------------------------
#define FA_SK 72
#define FA_SV 136
#define FA_SP 136

__global__ __launch_bounds__(256, 2) void attn_flash(
    const bf16* __restrict__ qkv, bf16* __restrict__ attnO)
{
    __shared__ bf16 KV[128 * FA_SK];
    __shared__ bf16 Ps[4 * 32 * FA_SP];

    bf16* Ks = KV;
    bf16* Vt = KV;

    const int t    = threadIdx.x;
    const int lane = t & 63;
    const int wv   = t >> 6;
    const int lr   = lane & 15;
    const int lq   = lane >> 4;
    const int qt   = blockIdx.x;
    const int h    = blockIdx.y & 15;
    const int b    = blockIdx.y >> 4;

    const size_t tokBase = (size_t)b * TS;

    short8 qf[2][2];
    #pragma unroll
    for (int mi = 0; mi < 2; mi++)
        #pragma unroll
        for (int kc = 0; kc < 2; kc++)
            qf[mi][kc] = *(const short8*)&qkv[
                (tokBase + qt * 128 + wv * 32 + mi * 16 + lr) * T3E
                + h * TD + kc * 32 + lq * 8];

    f32x4 oacc[2][4];
    #pragma unroll
    for (int mi = 0; mi < 2; mi++)
        #pragma unroll
        for (int ni = 0; ni < 4; ni++)
            oacc[mi][ni] = (f32x4){0.f, 0.f, 0.f, 0.f};
    float mrow[2][4], lrow[2][4];
    #pragma unroll
    for (int mi = 0; mi < 2; mi++)
        #pragma unroll
        for (int r = 0; r < 4; r++) { mrow[mi][r] = -1e30f; lrow[mi][r] = 0.f; }

    for (int it = 0; it < 16; it++) {
        const int kb0 = it * 128;
        __syncthreads();

        #pragma unroll
        for (int i = 0; i < 4; i++) {
            int l  = t + i * 256;
            int r  = l >> 3;
            int ch = (l & 7) * 8;
            *(uint4*)&Ks[r * FA_SK + ch] =
                *(const uint4*)&qkv[(tokBase + kb0 + r) * T3E + TE + h * TD + ch];
        }
        __syncthreads();

        f32x4 sacc[2][8];
        #pragma unroll
        for (int mi = 0; mi < 2; mi++)
            #pragma unroll
            for (int ni = 0; ni < 8; ni++)
                sacc[mi][ni] = (f32x4){0.f, 0.f, 0.f, 0.f};
        #pragma unroll
        for (int kc = 0; kc < 2; kc++) {
            short8 kf[8];
            #pragma unroll
            for (int ni = 0; ni < 8; ni++)
                kf[ni] = *(const short8*)&Ks[(ni * 16 + lr) * FA_SK + kc * 32 + lq * 8];
            #pragma unroll
            for (int mi = 0; mi < 2; mi++)
                #pragma unroll
                for (int ni = 0; ni < 8; ni++)
                    sacc[mi][ni] = __builtin_amdgcn_mfma_f32_16x16x32_bf16(
                        qf[mi][kc], kf[ni], sacc[mi][ni], 0, 0, 0);
        }

        uint4 vreg[4];
        const int vr  = t >> 1;
        const int vdc = (t & 1) * 32;
        #pragma unroll
        for (int i = 0; i < 4; i++)
            vreg[i] = *(const uint4*)&qkv[
                (tokBase + kb0 + vr) * T3E + 2 * TE + h * TD + vdc + i * 8];

        __syncthreads();

        {
            const bf16* vv = (const bf16*)vreg;
            #pragma unroll
            for (int j = 0; j < 32; j++)
                Vt[(vdc + j) * FA_SV + vr] = vv[j];
        }

        #pragma unroll
        for (int mi = 0; mi < 2; mi++) {
            #pragma unroll
            for (int rg = 0; rg < 4; rg++) {
                float rmax = -1e30f;
                #pragma unroll
                for (int ni = 0; ni < 8; ni++)
                    rmax = fmaxf(rmax, sacc[mi][ni][rg]);
                rmax *= 0.125f;
                #pragma unroll
                for (int m = 1; m <= 8; m <<= 1)
                    rmax = fmaxf(rmax, __shfl_xor(rmax, m, 64));
                float mnew  = fmaxf(mrow[mi][rg], rmax);
                float alpha = __expf(mrow[mi][rg] - mnew);
                mrow[mi][rg] = mnew;
                float rsum = 0.f;
                #pragma unroll
                for (int ni = 0; ni < 8; ni++) {
                    float p = __expf(sacc[mi][ni][rg] * 0.125f - mnew);
                    sacc[mi][ni][rg] = p;
                    rsum += p;
                }
                #pragma unroll
                for (int m = 1; m <= 8; m <<= 1)
                    rsum += __shfl_xor(rsum, m, 64);
                lrow[mi][rg] = lrow[mi][rg] * alpha + rsum;
                #pragma unroll
                for (int ni = 0; ni < 4; ni++)
                    oacc[mi][ni][rg] *= alpha;
            }
        }

        #pragma unroll
        for (int mi = 0; mi < 2; mi++)
            #pragma unroll
            for (int ni = 0; ni < 8; ni++)
                #pragma unroll
                for (int rg = 0; rg < 4; rg++)
                    Ps[(wv * 32 + mi * 16 + lq * 4 + rg) * FA_SP + ni * 16 + lr] =
                        __float2bfloat16(sacc[mi][ni][rg]);

        __syncthreads();

        #pragma unroll
        for (int kc = 0; kc < 4; kc++) {
            short8 pa[2], vb[4];
            #pragma unroll
            for (int mi = 0; mi < 2; mi++)
                pa[mi] = *(const short8*)&Ps[(wv * 32 + mi * 16 + lr) * FA_SP + kc * 32 + lq * 8];
            #pragma unroll
            for (int ni = 0; ni < 4; ni++)
                vb[ni] = *(const short8*)&Vt[(ni * 16 + lr) * FA_SV + kc * 32 + lq * 8];
            #pragma unroll
            for (int mi = 0; mi < 2; mi++)
                #pragma unroll
                for (int ni = 0; ni < 4; ni++)
                    oacc[mi][ni] = __builtin_amdgcn_mfma_f32_16x16x32_bf16(
                        pa[mi], vb[ni], oacc[mi][ni], 0, 0, 0);
        }
    }

    #pragma unroll
    for (int mi = 0; mi < 2; mi++) {
        #pragma unroll
        for (int ni = 0; ni < 4; ni++) {
            #pragma unroll
            for (int rg = 0; rg < 4; rg++) {
                float o = oacc[mi][ni][rg] / lrow[mi][rg];
                attnO[(tokBase + qt * 128 + wv * 32 + mi * 16 + lq * 4 + rg) * TE
                      + h * TD + ni * 16 + lr] = __float2bfloat16(o);
            }
        }
    }
}

// ---------------------------------------------------------------------------
// out = LayerNorm(a + p0 + p1) * g + beta; optionally also bf16 copy of out.
// One block per row of 1024.
// ---------------------------------------------------------------------------
__global__ __launch_bounds__(256) void add_ln3(
    const float* __restrict__ a, const float* __restrict__ p0,
    const float* __restrict__ p1, const float* __restrict__ g,
    const float* __restrict__ beta, float* __restrict__ out,
    bf16* __restrict__ outb)
{
    __shared__ float r1[256], r2[256];
    const int t = threadIdx.x;
    const size_t row = (size_t)blockIdx.x * TE;

    float4 va = *(const float4*)&a[row + t * 4];
    float4 v0 = *(const float4*)&p0[row + t * 4];
    float4 v1 = *(const float4*)&p1[row + t * 4];
    float v[4] = {va.x + v0.x + v1.x, va.y + v0.y + v1.y,
                  va.z + v0.z + v1.z, va.w + v0.w + v1.w};
    float s = 0.f, s2 = 0.f;
    #pragma unroll
    for (int i = 0; i < 4; i++) { s += v[i]; s2 += v[i] * v[i]; }
    r1[t] = s; r2[t] = s2;
    __syncthreads();
    for (int off = 128; off > 0; off >>= 1) {
        if (t < off) { r1[t] += r1[t + off]; r2[t] += r2[t + off]; }
        __syncthreads();
    }
    const float mu  = r1[0] * (1.f / 1024.f);
    const float var = r2[0] * (1.f / 1024.f) - mu * mu;
    const float rs  = rsqrtf(var + 1e-5f);
    float4 vg  = *(const float4*)&g[t * 4];
    float4 vbt = *(const float4*)&beta[t * 4];
    float o[4];
    o[0] = (v[0] - mu) * rs * vg.x + vbt.x;
    o[1] = (v[1] - mu) * rs * vg.y + vbt.y;
    o[2] = (v[2] - mu) * rs * vg.z + vbt.z;
    o[3] = (v[3] - mu) * rs * vg.w + vbt.w;
    *(float4*)&out[row + t * 4] = *(float4*)o;
    if (outb) {
        bf16 ob[4];
        #pragma unroll
        for (int i = 0; i < 4; i++) ob[i] = __float2bfloat16(o[i]);
        *(uint2*)&outb[row + t * 4] = *(uint2*)ob;
    }
}

// ---------------------------------------------------------------------------
extern "C" void kernel_launch(void* const* d_in, const int* in_sizes, int n_in,
                              void* d_out, int out_size, void* d_ws, size_t ws_size,
                              hipStream_t stream)
{
    const float* x     = (const float*)d_in[0];
    const float* w_qkv = (const float*)d_in[1];
    const float* b_qkv = (const float*)d_in[2];
    const float* w_out = (const float*)d_in[3];
    const float* b_out = (const float*)d_in[4];
    const float* g1    = (const float*)d_in[5];
    const float* beta1 = (const float*)d_in[6];
    const float* w_fc1 = (const float*)d_in[7];
    const float* b_fc1 = (const float*)d_in[8];
    const float* w_fc2 = (const float*)d_in[9];
    const float* b_fc2 = (const float*)d_in[10];
    const float* g2    = (const float*)d_in[11];
    const float* beta2 = (const float*)d_in[12];
    float* out = (float*)d_out;

    // workspace layout (byte offsets), ~120 MiB peak:
    //  [0,   32M)  : qkv bf16 (24M, steps 1-2)  then hbuf bf16 (32M, steps 5-6)
    //  [32M, 40M)  : attnO bf16 (8M)
    //  [40M, 72M)  : y0,y1 fp32 partials (steps 3-4) then ff0,ff1 (steps 6-7)
    //  [72M, 88M)  : xb bf16 (8M, step 1 only)  then x1 fp32 (16M, steps 4-7)
    //  [88M, 96M)  : x1b bf16 (8M, step 5)
    //  [96M, 120M) : bf16 weights: wqkvb 6M | woutb 2M | wfc1b 8M | wfc2b 8M
    char* wsb   = (char*)d_ws;
    bf16*  qkv   = (bf16*)(wsb);
    bf16*  hbuf  = (bf16*)(wsb);
    bf16*  attnO = (bf16*)(wsb + 33554432);
    float* y     = (float*)(wsb + 41943040);          // + partial stride 4096*1024
    float* ff    = y;
    bf16*  xb    = (bf16*)(wsb + 75497472);
    float* x1    = (float*)(wsb + 75497472);
    bf16*  x1b   = (bf16*)(wsb + 92274688);
    bf16*  wqkvb = (bf16*)(wsb + 100663296);
    bf16*  woutb = (bf16*)(wsb + 106954752);
    bf16*  wfc1b = (bf16*)(wsb + 109051904);
    bf16*  wfc2b = (bf16*)(wsb + 117440512);

    const int M = 2 * TS;               // 4096 tokens
    const size_t PART = (size_t)M * TE; // fp32 partial stride
    dim3 blk(256);

    // 0) converts (fp32 -> bf16)
    f2b<<<dim3(2048), blk, 0, stream>>>(x, xb);
    f2b<<<dim3(1536), blk, 0, stream>>>(w_qkv, wqkvb);
    f2b<<<dim3(512),  blk, 0, stream>>>(w_out, woutb);
    f2b<<<dim3(2048), blk, 0, stream>>>(w_fc1, wfc1b);
    f2b<<<dim3(2048), blk, 0, stream>>>(w_fc2, wfc2b);

    // 1) qkv = xb @ wqkvb^T + b_qkv
    gemm_bt<bf16, false><<<dim3(24, 32, 1), blk, 0, stream>>>(
        xb, wqkvb, b_qkv, qkv, M, T3E, TE, TE);
    // 2) flash attention
    attn_flash<<<dim3(TS / 128, 2 * TH), blk, 0, stream>>>(qkv, attnO);
    // 3) y{0,1} = attnO @ woutb^T (+b_out on z=0), split-K=2
    gemm_bt<float, false><<<dim3(8, 32, 2), blk, 0, stream>>>(
        attnO, woutb, b_out, y, M, TE, TE, TE / 2);
    // 4) x1 = LN(x + y0 + y1); also x1b (bf16)
    add_ln3<<<dim3(M), blk, 0, stream>>>(x, y, y + PART, g1, beta1, x1, x1b);
    // 5) hbuf = gelu(x1b @ wfc1b^T + b_fc1)
    gemm_bt<bf16, true><<<dim3(32, 32, 1), blk, 0, stream>>>(
        x1b, wfc1b, b_fc1, hbuf, M, 4096, TE, TE);
    // 6) ff{0,1} = hbuf @ wfc2b^T (+b_fc2 on z=0), split-K=2
    gemm_bt<float, false><<<dim3(8, 32, 2), blk, 0, stream>>>(
        hbuf, wfc2b, b_fc2, ff, M, TE, 4096, 2048);
    // 7) out = LN(x1 + ff0 + ff1)
    add_ln3<<<dim3(M), blk, 0, stream>>>(x1, ff, ff + PART, g2, beta2, out, nullptr);
}